// Round 7
// baseline (262.658 us; speedup 1.0000x reference)
//
#include <hip/hip_runtime.h>
#include <cstddef>
#include <cstdint>

typedef __attribute__((ext_vector_type(8))) short bf16x8;
typedef __attribute__((ext_vector_type(4))) float f32x4;

static __device__ __forceinline__ short f2bf(float f) {
    union { float f; unsigned u; } x;
    x.f = f;
    unsigned r = (x.u + 0x7FFFu + ((x.u >> 16) & 1u)) >> 16;  // RNE
    return (short)r;
}
static __device__ __forceinline__ short f2bf_fast(float f) {
    union { float f; unsigned u; } x;
    x.f = f;
    return (short)((x.u + 0x8000u) >> 16);
}

typedef __attribute__((address_space(3))) unsigned lds_u;
typedef const __attribute__((address_space(1))) unsigned glb_u;
static __device__ __forceinline__ void gld_lds16(const void* g, void* l) {
    __builtin_amdgcn_global_load_lds((glb_u*)g, (lds_u*)l, 16, 0, 0);
}

// ---------------------------------------------------------------------------
// prep: blocks [0,7168) convert x,ctx fp32->bf16; [7168,8448) transpose+convert
// weights to BT layout (Wk|Wv fused into wkvT [1024,768]).
// ---------------------------------------------------------------------------
__global__ __launch_bounds__(256) void prep_kernel(
    const float* __restrict__ x, const float* __restrict__ c,
    const float* __restrict__ Wq, const float* __restrict__ Wk,
    const float* __restrict__ Wv, const float* __restrict__ Wo,
    short* __restrict__ xb, short* __restrict__ cb,
    short* __restrict__ wqT, short* __restrict__ wkvT, short* __restrict__ woT)
{
    const int bid = blockIdx.x;
    const int tid = threadIdx.x;
    if (bid < 7168) {
        int i = bid * 256 + tid;                 // float4 index
        int nn1 = (8192 * 512) >> 2;
        const float* src; short* dst; int off;
        if (i < nn1) { src = x; dst = xb; off = i; }
        else { src = c; dst = cb; off = i - nn1; }
        float4 v = ((const float4*)src)[off];
        ushort4 w;
        w.x = (unsigned short)f2bf(v.x); w.y = (unsigned short)f2bf(v.y);
        w.z = (unsigned short)f2bf(v.z); w.w = (unsigned short)f2bf(v.w);
        ((ushort4*)dst)[off] = w;
        return;
    }
    __shared__ float T[32][33];
    int w = bid - 7168;
    const float* src; short* dst; int R, t;
    if (w < 256)       { src = Wq; dst = wqT;  R = 512; t = w; }
    else if (w < 640)  { src = Wk; dst = wkvT; R = 768; t = w - 256; }
    else if (w < 1024) { src = Wv; dst = wkvT + (size_t)512 * 768; R = 768; t = w - 640; }
    else               { src = Wo; dst = woT;  R = 512; t = w - 1024; }
    const int xt = t & 15, yt = t >> 4;
    {
        int r = tid >> 3, c4 = (tid & 7) * 4;
        float4 v = *(const float4*)&src[(size_t)(yt * 32 + r) * 512 + xt * 32 + c4];
        T[r][c4] = v.x; T[r][c4 + 1] = v.y; T[r][c4 + 2] = v.z; T[r][c4 + 3] = v.w;
    }
    __syncthreads();
    {
        int cc = tid >> 3, r4 = (tid & 7) * 4;
        ushort4 o;
        o.x = (unsigned short)f2bf(T[r4][cc]);     o.y = (unsigned short)f2bf(T[r4 + 1][cc]);
        o.z = (unsigned short)f2bf(T[r4 + 2][cc]); o.w = (unsigned short)f2bf(T[r4 + 3][cc]);
        *(ushort4*)&dst[(size_t)(xt * 32 + cc) * R + yt * 32 + r4] = o;
    }
}

// ---------------------------------------------------------------------------
// 64x64-tile hybrid GEMM core (4 blocks/CU). 4 waves, each 16 rows x 64 cols
// (acc 1x4). A: global->LDS DMA, BK=64 windows, 16 KB dbuf, one barrier per
// window. B: reg-streamed from L2 (16B frags, prefetched ahead).
// acc[j] covers cols bn + j*16+lm, rows bm + wave*16 + quad*4 + r.
// ---------------------------------------------------------------------------
static __device__ __forceinline__ void gemm64_core(
    const short* __restrict__ A, const short* __restrict__ BT, int K,
    int bm, int bn, short* As, f32x4 acc[4])
{
    const int tid = threadIdx.x, lane = tid & 63, wave = tid >> 6;
    const int lm = lane & 15, quad = lane >> 4;
    const int cs = tid >> 6, rs = tid & 63;      // staging: 2 chunks/thread

    const short* Ag = A + (size_t)(bm + rs) * K;
    const short* Bb = BT + (size_t)(bn + lm) * K + quad * 8;
    const size_t rsB = (size_t)16 * K;

    // prologue: DMA window 0; load B(w0, half0)
    gld_lds16(Ag + cs * 8,       As + (cs * 64 + rs) * 8);
    gld_lds16(Ag + (cs + 4) * 8, As + ((cs + 4) * 64 + rs) * 8);
    bf16x8 b0[4], b1[4], b2[4];
    #pragma unroll
    for (int j = 0; j < 4; ++j) b0[j] = *(const bf16x8*)(Bb + j * rsB);

    const int nw = K >> 6;
    for (int w = 0; w < nw; ++w) {
        short* Ac = As + (w & 1) * 4096;
        __syncthreads();                          // drains DMA(w)
        if (w + 1 < nw) {
            short* An = As + ((w + 1) & 1) * 4096;
            const short* Agn = Ag + (w + 1) * 64;
            gld_lds16(Agn + cs * 8,       An + (cs * 64 + rs) * 8);
            gld_lds16(Agn + (cs + 4) * 8, An + ((cs + 4) * 64 + rs) * 8);
        }
        #pragma unroll
        for (int j = 0; j < 4; ++j)
            b1[j] = *(const bf16x8*)(Bb + w * 64 + 32 + j * rsB);
        bf16x8 af0 = *(const bf16x8*)&Ac[(quad * 64 + wave * 16 + lm) * 8];
        #pragma unroll
        for (int j = 0; j < 4; ++j)
            acc[j] = __builtin_amdgcn_mfma_f32_16x16x32_bf16(af0, b0[j], acc[j], 0, 0, 0);
        if (w + 1 < nw) {
            #pragma unroll
            for (int j = 0; j < 4; ++j)
                b2[j] = *(const bf16x8*)(Bb + (w + 1) * 64 + j * rsB);
        }
        bf16x8 af1 = *(const bf16x8*)&Ac[((4 + quad) * 64 + wave * 16 + lm) * 8];
        #pragma unroll
        for (int j = 0; j < 4; ++j)
            acc[j] = __builtin_amdgcn_mfma_f32_16x16x32_bf16(af1, b1[j], acc[j], 0, 0, 0);
        #pragma unroll
        for (int j = 0; j < 4; ++j) b0[j] = b2[j];
    }
}

// ---------------------------------------------------------------------------
// KV projection: [k|v] = cb @ wkvT. Grid 1024 (64 M-tiles x 16 N-tiles).
// k-half (bn<512) -> kb [4096][512]. v-half -> vT [4][512][1024] via LDS
// 64x64 transpose in the epilogue (coalesced writes).
// ---------------------------------------------------------------------------
__global__ __launch_bounds__(256) void kvgemm_kernel(
    const short* __restrict__ cb, const short* __restrict__ wkvT,
    short* __restrict__ kb, short* __restrict__ vT)
{
    __shared__ short As[2 * 4096];
    const int bid = blockIdx.x;
    const int bm = (bid >> 4) * 64, bn = (bid & 15) * 64;

    f32x4 acc[4] = {};
    gemm64_core(cb, wkvT, 768, bm, bn, As, acc);

    const int tid = threadIdx.x, lane = tid & 63, wave = tid >> 6;
    const int lm = lane & 15, quad = lane >> 4;

    if (bn < 512) {   // k-half: direct coalesced store
        #pragma unroll
        for (int j = 0; j < 4; ++j) {
            int col = bn + j * 16 + lm;
            #pragma unroll
            for (int r = 0; r < 4; ++r)
                kb[(size_t)(bm + wave * 16 + quad * 4 + r) * 512 + col] = f2bf(acc[j][r]);
        }
    } else {          // v-half: transpose via LDS (stride 72 pad)
        short* T = As;   // 64*72 = 4608 shorts <= 8192
        __syncthreads();                 // all waves done reading As
        #pragma unroll
        for (int j = 0; j < 4; ++j)
            #pragma unroll
            for (int r = 0; r < 4; ++r)
                T[(wave * 16 + quad * 4 + r) * 72 + j * 16 + lm] = f2bf(acc[j][r]);
        __syncthreads();
        const int d = tid >> 2, kv0 = (tid & 3) * 16;
        short vals[16];
        #pragma unroll
        for (int i = 0; i < 16; ++i) vals[i] = T[(kv0 + i) * 72 + d];
        const int b = bm >> 10;
        size_t base = ((size_t)(b * 512 + (bn - 512) + d)) * 1024 + (bm & 1023) + kv0;
        *(bf16x8*)&vT[base]     = *(bf16x8*)&vals[0];
        *(bf16x8*)&vT[base + 8] = *(bf16x8*)&vals[8];
    }
}

// ---------------------------------------------------------------------------
// Output projection: out = ob@woT + bo (fp32). Grid 1024 (128 x 8 tiles).
// ---------------------------------------------------------------------------
__global__ __launch_bounds__(256) void ogemm_kernel(
    const short* __restrict__ ob, const short* __restrict__ woT,
    const float* __restrict__ bias, float* __restrict__ out)
{
    __shared__ short As[2 * 4096];
    const int bid = blockIdx.x;
    const int bm = (bid >> 3) * 64, bn = (bid & 7) * 64;

    f32x4 acc[4] = {};
    gemm64_core(ob, woT, 512, bm, bn, As, acc);

    const int lane = threadIdx.x & 63, wave = threadIdx.x >> 6;
    const int lm = lane & 15, quad = lane >> 4;
    #pragma unroll
    for (int j = 0; j < 4; ++j) {
        int col = bn + j * 16 + lm;
        float bv = bias[col];
        #pragma unroll
        for (int r = 0; r < 4; ++r)
            out[(size_t)(bm + wave * 16 + quad * 4 + r) * 512 + col] = acc[j][r] + bv;
    }
}

// ---------------------------------------------------------------------------
// Flash attention with FUSED Q-projection. Block = (b,h,64 q-rows), 4 waves.
// Q-proj: wave computes its 16 q-rows x 64 head-cols via reg-streaming
// mini-GEMM (A = xb rows, B = wqT rows hcol..hcol+64, both L2/L3-resident),
// result goes through the verified C->A swizzle (P-buffer path) into qf.
// Then the round-5 flash loop: fixed-max softmax, K/V dbuf, P LDS round-trip.
// ---------------------------------------------------------------------------
__global__ __launch_bounds__(256) void attn_kernel(
    const short* __restrict__ xb, const short* __restrict__ wqT,
    const short* __restrict__ kb, const short* __restrict__ vT,
    short* __restrict__ o)
{
    __shared__ short Qs[4096];          // per-wave Q/P swizzle buffers
    __shared__ short Ks[2 * 4096];
    __shared__ short Vs[2 * 4096];

    const int tid  = threadIdx.x;
    const int lane = tid & 63;
    const int wave = tid >> 6;
    const int lm   = lane & 15;
    const int quad = lane >> 4;
    const int qt = blockIdx.x, h = blockIdx.y, b = blockIdx.z;
    const size_t qrow0 = (size_t)b * 2048 + qt * 64;
    const size_t krow0 = (size_t)b * 1024;
    const int hcol = h * 64;
    const size_t vrow0 = ((size_t)b * 8 + h) * 64;

    // issue K/V tile-0 DMA first (overlaps Q-proj compute)
    #pragma unroll
    for (int p = 0; p < 2; ++p) {
        int idx = p * 256 + tid;
        int c = idx >> 6, r = idx & 63;
        gld_lds16(&kb[(krow0 + r) * 512 + hcol + c * 8], &Ks[idx * 8]);
        gld_lds16(&vT[(vrow0 + r) * 1024 + c * 8], &Vs[idx * 8]);
    }

    short* Pw = &Qs[wave * 1024];
    const int pr0 = lm * 64 + ((quad ^ (lm & 7)) << 3);
    const int pr1 = lm * 64 + (((quad + 4) ^ (lm & 7)) << 3);
    int rowo[4], swz[4];
    #pragma unroll
    for (int r = 0; r < 4; ++r) {
        int row = quad * 4 + r;
        rowo[r] = row * 64 + (lm & 7);
        swz[r]  = row & 7;
    }

    // ---- Q-proj mini-GEMM: rows qrow0 + wave*16 + lm, cols hcol + j*16+lm ----
    {
        const short* Axp = xb + (qrow0 + wave * 16 + lm) * 512 + quad * 8;
        const short* Bqp = wqT + (size_t)(hcol + lm) * 512 + quad * 8;
        f32x4 qacc[4] = {};
        bf16x8 a0 = *(const bf16x8*)Axp;
        bf16x8 bq[4], bqn[4];
        #pragma unroll
        for (int j = 0; j < 4; ++j) bq[j] = *(const bf16x8*)(Bqp + (size_t)j * 16 * 512);
        bf16x8 a1;
        for (int kk = 0; kk < 16; ++kk) {
            if (kk + 1 < 16) {
                a1 = *(const bf16x8*)(Axp + (kk + 1) * 32);
                #pragma unroll
                for (int j = 0; j < 4; ++j)
                    bqn[j] = *(const bf16x8*)(Bqp + (kk + 1) * 32 + (size_t)j * 16 * 512);
            }
            #pragma unroll
            for (int j = 0; j < 4; ++j)
                qacc[j] = __builtin_amdgcn_mfma_f32_16x16x32_bf16(a0, bq[j], qacc[j], 0, 0, 0);
            a0 = a1;
            #pragma unroll
            for (int j = 0; j < 4; ++j) bq[j] = bqn[j];
        }
        // C-layout -> swizzled LDS -> A-layout qf (wave-private, no barrier)
        #pragma unroll
        for (int r = 0; r < 4; ++r)
            #pragma unroll
            for (int j = 0; j < 4; ++j) {
                int cc = (2 * j + (lm >> 3)) ^ swz[r];
                Pw[rowo[r] + (cc << 3)] = f2bf(qacc[j][r]);
            }
    }
    bf16x8 qf0 = *(const bf16x8*)&Pw[pr0];
    bf16x8 qf1 = *(const bf16x8*)&Pw[pr1];

    constexpr float C1 = 0.18033688f;   // 0.125 * log2(e)
    constexpr float C2 = 11.5415603f;   // 8 * log2(e)

    f32x4 oacc[4] = {};
    float lrow[4] = {0.0f, 0.0f, 0.0f, 0.0f};

    for (int t = 0; t < 16; ++t) {
        const short* Kc = &Ks[(t & 1) * 4096];
        const short* Vc = &Vs[(t & 1) * 4096];
        __syncthreads();
        if (t + 1 < 16) {
            short* Kn = &Ks[((t + 1) & 1) * 4096];
            short* Vn = &Vs[((t + 1) & 1) * 4096];
            #pragma unroll
            for (int p = 0; p < 2; ++p) {
                int idx = p * 256 + tid;
                int c = idx >> 6, r = idx & 63;
                gld_lds16(&kb[(krow0 + (t + 1) * 64 + r) * 512 + hcol + c * 8], &Kn[idx * 8]);
                gld_lds16(&vT[(vrow0 + r) * 1024 + (t + 1) * 64 + c * 8], &Vn[idx * 8]);
            }
        }

        f32x4 sacc[4] = {};
        #pragma unroll
        for (int j = 0; j < 4; ++j) {
            bf16x8 kf0 = *(const bf16x8*)&Kc[((0 + quad) * 64 + j * 16 + lm) * 8];
            bf16x8 kf1 = *(const bf16x8*)&Kc[((4 + quad) * 64 + j * 16 + lm) * 8];
            sacc[j] = __builtin_amdgcn_mfma_f32_16x16x32_bf16(qf0, kf0, sacc[j], 0, 0, 0);
            sacc[j] = __builtin_amdgcn_mfma_f32_16x16x32_bf16(qf1, kf1, sacc[j], 0, 0, 0);
        }

        #pragma unroll
        for (int r = 0; r < 4; ++r) {
            float lsum = 0.0f;
            #pragma unroll
            for (int j = 0; j < 4; ++j) {
                float pv = exp2f(fmaf(sacc[j][r], C1, -C2));
                lsum += pv;
                int cc = (2 * j + (lm >> 3)) ^ swz[r];
                Pw[rowo[r] + (cc << 3)] = f2bf_fast(pv);
            }
            lrow[r] += lsum;
        }
        bf16x8 pf0 = *(const bf16x8*)&Pw[pr0];
        bf16x8 pf1 = *(const bf16x8*)&Pw[pr1];

        #pragma unroll
        for (int j = 0; j < 4; ++j) {
            bf16x8 vf0 = *(const bf16x8*)&Vc[((0 + quad) * 64 + j * 16 + lm) * 8];
            bf16x8 vf1 = *(const bf16x8*)&Vc[((4 + quad) * 64 + j * 16 + lm) * 8];
            oacc[j] = __builtin_amdgcn_mfma_f32_16x16x32_bf16(pf0, vf0, oacc[j], 0, 0, 0);
            oacc[j] = __builtin_amdgcn_mfma_f32_16x16x32_bf16(pf1, vf1, oacc[j], 0, 0, 0);
        }
    }

    float inv[4];
    #pragma unroll
    for (int r = 0; r < 4; ++r) {
        float s = lrow[r];
        #pragma unroll
        for (int d = 1; d < 16; d <<= 1) s += __shfl_xor(s, d);
        inv[r] = 1.0f / s;
    }
    #pragma unroll
    for (int j = 0; j < 4; ++j) {
        int col = hcol + j * 16 + lm;
        #pragma unroll
        for (int r = 0; r < 4; ++r) {
            size_t row = qrow0 + wave * 16 + quad * 4 + r;
            o[row * 512 + col] = f2bf(oacc[j][r] * inv[r]);
        }
    }
}

// ---------------------------------------------------------------------------
extern "C" void kernel_launch(void* const* d_in, const int* in_sizes, int n_in,
                              void* d_out, int out_size, void* d_ws, size_t ws_size,
                              hipStream_t stream)
{
    const float* x   = (const float*)d_in[0];
    const float* ctx = (const float*)d_in[1];
    const float* Wq  = (const float*)d_in[2];
    const float* Wk  = (const float*)d_in[3];
    const float* Wv  = (const float*)d_in[4];
    const float* Wo  = (const float*)d_in[5];
    const float* bo  = (const float*)d_in[6];

    char* ws = (char*)d_ws;                                        // 32.5 MB used
    short* xb   = (short*)(ws);                                    // 8 MB
    short* cb   = (short*)(ws + (8u << 20));                       // 6 MB
    short* wqT  = (short*)(ws + (14u << 20));                      // 0.5 MB
    short* wkvT = (short*)(ws + (14u << 20) + (512u << 10));       // 1.5 MB
    short* woT  = (short*)(ws + (16u << 20));                      // 0.5 MB
    short* kb   = (short*)(ws + (16u << 20) + (512u << 10));       // 4 MB
    short* vT   = (short*)(ws + (20u << 20) + (512u << 10));       // 4 MB
    short* ob   = (short*)(ws + (24u << 20) + (512u << 10));       // 8 MB

    prep_kernel<<<8448, 256, 0, stream>>>(x, ctx, Wq, Wk, Wv, Wo,
                                          xb, cb, wqT, wkvT, woT);
    kvgemm_kernel<<<1024, 256, 0, stream>>>(cb, wkvT, kb, vT);
    attn_kernel<<<dim3(32, 8, 4), 256, 0, stream>>>(xb, wqT, kb, vT, ob);
    ogemm_kernel<<<1024, 256, 0, stream>>>(ob, woT, bo, (float*)d_out);
}

// Round 8
// 195.724 us; speedup vs baseline: 1.3420x; 1.3420x over previous
//
#include <hip/hip_runtime.h>
#include <cstddef>
#include <cstdint>

typedef __attribute__((ext_vector_type(8))) short bf16x8;
typedef __attribute__((ext_vector_type(4))) float f32x4;

static __device__ __forceinline__ short f2bf(float f) {
    union { float f; unsigned u; } x;
    x.f = f;
    unsigned r = (x.u + 0x7FFFu + ((x.u >> 16) & 1u)) >> 16;  // RNE
    return (short)r;
}
static __device__ __forceinline__ short f2bf_fast(float f) {
    union { float f; unsigned u; } x;
    x.f = f;
    return (short)((x.u + 0x8000u) >> 16);
}

typedef __attribute__((address_space(3))) unsigned lds_u;
typedef const __attribute__((address_space(1))) unsigned glb_u;
static __device__ __forceinline__ void gld_lds16(const void* g, void* l) {
    __builtin_amdgcn_global_load_lds((glb_u*)g, (lds_u*)l, 16, 0, 0);
}

// ---------------------------------------------------------------------------
// prep: blocks [0,7168) convert x,ctx fp32->bf16; [7168,8448) transpose+convert
// weights to BT layout (Wk|Wv fused into wkvT [1024,768]).
// ---------------------------------------------------------------------------
__global__ __launch_bounds__(256) void prep_kernel(
    const float* __restrict__ x, const float* __restrict__ c,
    const float* __restrict__ Wq, const float* __restrict__ Wk,
    const float* __restrict__ Wv, const float* __restrict__ Wo,
    short* __restrict__ xb, short* __restrict__ cb,
    short* __restrict__ wqT, short* __restrict__ wkvT, short* __restrict__ woT)
{
    const int bid = blockIdx.x;
    const int tid = threadIdx.x;
    if (bid < 7168) {
        int i = bid * 256 + tid;                 // float4 index
        int nn1 = (8192 * 512) >> 2;
        const float* src; short* dst; int off;
        if (i < nn1) { src = x; dst = xb; off = i; }
        else { src = c; dst = cb; off = i - nn1; }
        float4 v = ((const float4*)src)[off];
        ushort4 w;
        w.x = (unsigned short)f2bf(v.x); w.y = (unsigned short)f2bf(v.y);
        w.z = (unsigned short)f2bf(v.z); w.w = (unsigned short)f2bf(v.w);
        ((ushort4*)dst)[off] = w;
        return;
    }
    __shared__ float T[32][33];
    int w = bid - 7168;
    const float* src; short* dst; int R, t;
    if (w < 256)       { src = Wq; dst = wqT;  R = 512; t = w; }
    else if (w < 640)  { src = Wk; dst = wkvT; R = 768; t = w - 256; }
    else if (w < 1024) { src = Wv; dst = wkvT + (size_t)512 * 768; R = 768; t = w - 640; }
    else               { src = Wo; dst = woT;  R = 512; t = w - 1024; }
    const int xt = t & 15, yt = t >> 4;
    {
        int r = tid >> 3, c4 = (tid & 7) * 4;
        float4 v = *(const float4*)&src[(size_t)(yt * 32 + r) * 512 + xt * 32 + c4];
        T[r][c4] = v.x; T[r][c4 + 1] = v.y; T[r][c4 + 2] = v.z; T[r][c4 + 3] = v.w;
    }
    __syncthreads();
    {
        int cc = tid >> 3, r4 = (tid & 7) * 4;
        ushort4 o;
        o.x = (unsigned short)f2bf(T[r4][cc]);     o.y = (unsigned short)f2bf(T[r4 + 1][cc]);
        o.z = (unsigned short)f2bf(T[r4 + 2][cc]); o.w = (unsigned short)f2bf(T[r4 + 3][cc]);
        *(ushort4*)&dst[(size_t)(xt * 32 + cc) * R + yt * 32 + r4] = o;
    }
}

// ---------------------------------------------------------------------------
// V transpose (bf16): kvb v-half [4][1024][512] (ld 1024) -> vT [4][512][1024]
// ---------------------------------------------------------------------------
__global__ __launch_bounds__(256) void vtrans_kernel(
    const short* __restrict__ v, short* __restrict__ vT)
{
    __shared__ short T[32][33];
    const int b = blockIdx.z, yt = blockIdx.y, xt = blockIdx.x;
    const int tid = threadIdx.x;
    {
        int r = tid >> 3, c4 = (tid & 7) * 4;
        ushort4 vv = *(const ushort4*)&v[((size_t)(b * 1024 + yt * 32 + r)) * 1024 + xt * 32 + c4];
        T[r][c4] = (short)vv.x; T[r][c4 + 1] = (short)vv.y;
        T[r][c4 + 2] = (short)vv.z; T[r][c4 + 3] = (short)vv.w;
    }
    __syncthreads();
    {
        int cc = tid >> 3, r4 = (tid & 7) * 4;
        ushort4 w;
        w.x = (unsigned short)T[r4][cc];     w.y = (unsigned short)T[r4 + 1][cc];
        w.z = (unsigned short)T[r4 + 2][cc]; w.w = (unsigned short)T[r4 + 3][cc];
        *(ushort4*)&vT[((size_t)(b * 512 + xt * 32 + cc)) * 1024 + yt * 32 + r4] = w;
    }
}

// ---------------------------------------------------------------------------
// 64x128-tile GEMM (r3 core, retiled for 4 blocks/CU). 4 waves (2x2: 32x64
// each, acc 2x4). BK=32, both A and B DMA-staged, dbuf, 1 barrier/window.
// LDS 24 KB. 3 DMA instr/thread/window (A1 + B2), 12 KB staged per window.
// ---------------------------------------------------------------------------
static __device__ __forceinline__ void gemm_core64x128(
    const short* __restrict__ A, const short* __restrict__ BT, int K,
    int bm, int bn, short* As, short* Bs, f32x4 acc[2][4])
{
    const int tid = threadIdx.x, lane = tid & 63, wave = tid >> 6;
    const int lm = lane & 15, quad = lane >> 4;
    const int wm = (wave >> 1) * 32, wn = (wave & 1) * 64;
    const int ca = tid >> 6, ra = tid & 63;      // A staging: 1 chunk/thread
    const int cb = tid >> 7, rb = tid & 127;     // B staging: 2 chunks/thread

    // prologue: window 0 into buf 0
    {
        gld_lds16(&A[(size_t)(bm + ra) * K + ca * 8], &As[(ca * 64 + ra) * 8]);
        const short* Bg = &BT[(size_t)(bn + rb) * K];
        gld_lds16(Bg + cb * 8,       &Bs[(cb * 128 + rb) * 8]);
        gld_lds16(Bg + (cb + 2) * 8, &Bs[((cb + 2) * 128 + rb) * 8]);
    }

    const int nw = K >> 5;
    for (int w = 0; w < nw; ++w) {
        short* Ac = As + (w & 1) * 2048;
        short* Bc = Bs + (w & 1) * 4096;
        __syncthreads();                          // cur buf ready; prev reads done
        if (w + 1 < nw) {
            short* An = As + ((w + 1) & 1) * 2048;
            short* Bn = Bs + ((w + 1) & 1) * 4096;
            int k0 = (w + 1) * 32;
            gld_lds16(&A[(size_t)(bm + ra) * K + k0 + ca * 8], &An[(ca * 64 + ra) * 8]);
            const short* Bg = &BT[(size_t)(bn + rb) * K + k0];
            gld_lds16(Bg + cb * 8,       &Bn[(cb * 128 + rb) * 8]);
            gld_lds16(Bg + (cb + 2) * 8, &Bn[((cb + 2) * 128 + rb) * 8]);
        }
        bf16x8 af[2], bfr[4];
        #pragma unroll
        for (int i = 0; i < 2; ++i)
            af[i] = *(const bf16x8*)&Ac[(quad * 64 + wm + i * 16 + lm) * 8];
        #pragma unroll
        for (int j = 0; j < 4; ++j)
            bfr[j] = *(const bf16x8*)&Bc[(quad * 128 + wn + j * 16 + lm) * 8];
        #pragma unroll
        for (int i = 0; i < 2; ++i)
            #pragma unroll
            for (int j = 0; j < 4; ++j)
                acc[i][j] = __builtin_amdgcn_mfma_f32_16x16x32_bf16(
                    af[i], bfr[j], acc[i][j], 0, 0, 0);
    }
}

// Fused Q + KV projection. Grid 1024 = 4 blocks/CU.
// [0,512): q = xb@wqT, tiles (128 M x 4 N). [512,1024): kv = cb@wkvT (64 x 8).
__global__ __launch_bounds__(256, 4) void qkv_kernel(
    const short* __restrict__ xb, const short* __restrict__ cb,
    const short* __restrict__ wqT, const short* __restrict__ wkvT,
    short* __restrict__ qb, short* __restrict__ kvb)
{
    __shared__ short As[2 * 2048];
    __shared__ short Bs[2 * 4096];
    const int bid = blockIdx.x;
    const short *A, *BT; short* C; int K, ldc, bm, bn;
    if (bid < 512) { A = xb; BT = wqT;  C = qb;  K = 512; ldc = 512;
                     bm = (bid >> 2) * 64; bn = (bid & 3) * 128; }
    else { int b2 = bid - 512; A = cb; BT = wkvT; C = kvb; K = 768; ldc = 1024;
           bm = (b2 >> 3) * 64; bn = (b2 & 7) * 128; }

    f32x4 acc[2][4] = {};
    gemm_core64x128(A, BT, K, bm, bn, As, Bs, acc);

    const int lane = threadIdx.x & 63, wave = threadIdx.x >> 6;
    const int lm = lane & 15, quad = lane >> 4;
    const int wm = (wave >> 1) * 32, wn = (wave & 1) * 64;
    #pragma unroll
    for (int j = 0; j < 4; ++j) {
        int col = bn + wn + j * 16 + lm;
        #pragma unroll
        for (int i = 0; i < 2; ++i) {
            int row0 = bm + wm + i * 16 + quad * 4;
            #pragma unroll
            for (int r = 0; r < 4; ++r)
                C[(size_t)(row0 + r) * ldc + col] = f2bf(acc[i][j][r]);
        }
    }
}

// ---------------------------------------------------------------------------
// Output projection: out = ob@woT + bo (fp32). 64x64 tiles, grid 1024
// (128 M x 8 N) = 4 blocks/CU. 4 waves as 16-row stripes, acc 1x4.
// BK=32, A+B DMA, dbuf 16 KB, 2 DMA/thread/window.
// ---------------------------------------------------------------------------
__global__ __launch_bounds__(256, 4) void ogemm_kernel(
    const short* __restrict__ ob, const short* __restrict__ woT,
    const float* __restrict__ bias, float* __restrict__ out)
{
    __shared__ short As[2 * 2048];
    __shared__ short Bs[2 * 2048];
    const int bid = blockIdx.x;
    const int bm = (bid >> 3) * 64, bn = (bid & 7) * 64;
    const int tid = threadIdx.x, lane = tid & 63, wave = tid >> 6;
    const int lm = lane & 15, quad = lane >> 4;
    const int cs = tid >> 6, rs = tid & 63;      // staging: 1 chunk each for A,B

    constexpr int K = 512;
    f32x4 acc[4] = {};

    // prologue
    gld_lds16(&ob[(size_t)(bm + rs) * K + cs * 8],  &As[(cs * 64 + rs) * 8]);
    gld_lds16(&woT[(size_t)(bn + rs) * K + cs * 8], &Bs[(cs * 64 + rs) * 8]);

    const int nw = K >> 5;
    for (int w = 0; w < nw; ++w) {
        short* Ac = As + (w & 1) * 2048;
        short* Bc = Bs + (w & 1) * 2048;
        __syncthreads();
        if (w + 1 < nw) {
            short* An = As + ((w + 1) & 1) * 2048;
            short* Bn = Bs + ((w + 1) & 1) * 2048;
            int k0 = (w + 1) * 32;
            gld_lds16(&ob[(size_t)(bm + rs) * K + k0 + cs * 8],  &An[(cs * 64 + rs) * 8]);
            gld_lds16(&woT[(size_t)(bn + rs) * K + k0 + cs * 8], &Bn[(cs * 64 + rs) * 8]);
        }
        bf16x8 af = *(const bf16x8*)&Ac[(quad * 64 + wave * 16 + lm) * 8];
        #pragma unroll
        for (int j = 0; j < 4; ++j) {
            bf16x8 bf = *(const bf16x8*)&Bc[(quad * 64 + j * 16 + lm) * 8];
            acc[j] = __builtin_amdgcn_mfma_f32_16x16x32_bf16(af, bf, acc[j], 0, 0, 0);
        }
    }

    #pragma unroll
    for (int j = 0; j < 4; ++j) {
        int col = bn + j * 16 + lm;
        float bv = bias[col];
        #pragma unroll
        for (int r = 0; r < 4; ++r)
            out[(size_t)(bm + wave * 16 + quad * 4 + r) * 512 + col] = acc[j][r] + bv;
    }
}

// ---------------------------------------------------------------------------
// Flash attention (round-5/6 proven, 49.1 us). Block = (b,h,64 q-rows),
// 4 waves. Fixed-max softmax exp2(s*C1 - C2); K/V dbuf; P via swizzled LDS.
// ---------------------------------------------------------------------------
__global__ __launch_bounds__(256) void attn_kernel(
    const short* __restrict__ q, const short* __restrict__ k,
    const short* __restrict__ vT, short* __restrict__ o)
{
    __shared__ short Qs[4096];          // Q staging, then per-wave P buffers
    __shared__ short Ks[2 * 4096];
    __shared__ short Vs[2 * 4096];

    const int tid  = threadIdx.x;
    const int lane = tid & 63;
    const int wave = tid >> 6;
    const int lm   = lane & 15;
    const int quad = lane >> 4;
    const int qt = blockIdx.x, h = blockIdx.y, b = blockIdx.z;
    const size_t qrow0 = (size_t)b * 2048 + qt * 64;
    const size_t krow0 = (size_t)b * 1024;
    const int hcol = h * 64;
    const size_t vrow0 = ((size_t)b * 8 + h) * 64;

    #pragma unroll
    for (int p = 0; p < 2; ++p) {
        int idx = p * 256 + tid;
        int c = idx >> 6, r = idx & 63;
        gld_lds16(&q[(qrow0 + r) * 512 + hcol + c * 8], &Qs[idx * 8]);
        gld_lds16(&k[(krow0 + r) * 1024 + hcol + c * 8], &Ks[idx * 8]);
        gld_lds16(&vT[(vrow0 + r) * 1024 + c * 8], &Vs[idx * 8]);
    }
    __syncthreads();
    bf16x8 qf0 = *(const bf16x8*)&Qs[((0 + quad) * 64 + wave * 16 + lm) * 8];
    bf16x8 qf1 = *(const bf16x8*)&Qs[((4 + quad) * 64 + wave * 16 + lm) * 8];

    short* Pw = &Qs[wave * 1024];
    const int pr0 = lm * 64 + ((quad ^ (lm & 7)) << 3);
    const int pr1 = lm * 64 + (((quad + 4) ^ (lm & 7)) << 3);

    constexpr float C1 = 0.18033688f;   // 0.125 * log2(e)
    constexpr float C2 = 11.5415603f;   // 8 * log2(e)

    f32x4 oacc[4] = {};
    float lrow[4] = {0.0f, 0.0f, 0.0f, 0.0f};

    for (int t = 0; t < 16; ++t) {
        const short* Kc = &Ks[(t & 1) * 4096];
        const short* Vc = &Vs[(t & 1) * 4096];
        __syncthreads();
        if (t + 1 < 16) {
            short* Kn = &Ks[((t + 1) & 1) * 4096];
            short* Vn = &Vs[((t + 1) & 1) * 4096];
            #pragma unroll
            for (int p = 0; p < 2; ++p) {
                int idx = p * 256 + tid;
                int c = idx >> 6, r = idx & 63;
                gld_lds16(&k[(krow0 + (t + 1) * 64 + r) * 1024 + hcol + c * 8], &Kn[idx * 8]);
                gld_lds16(&vT[(vrow0 + r) * 1024 + (t + 1) * 64 + c * 8], &Vn[idx * 8]);
            }
        }

        f32x4 sacc[4] = {};
        #pragma unroll
        for (int j = 0; j < 4; ++j) {
            bf16x8 kf0 = *(const bf16x8*)&Kc[((0 + quad) * 64 + j * 16 + lm) * 8];
            bf16x8 kf1 = *(const bf16x8*)&Kc[((4 + quad) * 64 + j * 16 + lm) * 8];
            sacc[j] = __builtin_amdgcn_mfma_f32_16x16x32_bf16(qf0, kf0, sacc[j], 0, 0, 0);
            sacc[j] = __builtin_amdgcn_mfma_f32_16x16x32_bf16(qf1, kf1, sacc[j], 0, 0, 0);
        }

        #pragma unroll
        for (int r = 0; r < 4; ++r) {
            int row = quad * 4 + r;
            int rsw = (row & 7);
            float lsum = 0.0f;
            #pragma unroll
            for (int j = 0; j < 4; ++j) {
                float pv = exp2f(fmaf(sacc[j][r], C1, -C2));
                lsum += pv;
                int cc = (2 * j + (lm >> 3)) ^ rsw;
                Pw[row * 64 + (cc << 3) + (lm & 7)] = f2bf_fast(pv);
            }
            lrow[r] += lsum;
        }
        bf16x8 pf0 = *(const bf16x8*)&Pw[pr0];
        bf16x8 pf1 = *(const bf16x8*)&Pw[pr1];

        #pragma unroll
        for (int j = 0; j < 4; ++j) {
            bf16x8 vf0 = *(const bf16x8*)&Vc[((0 + quad) * 64 + j * 16 + lm) * 8];
            bf16x8 vf1 = *(const bf16x8*)&Vc[((4 + quad) * 64 + j * 16 + lm) * 8];
            oacc[j] = __builtin_amdgcn_mfma_f32_16x16x32_bf16(pf0, vf0, oacc[j], 0, 0, 0);
            oacc[j] = __builtin_amdgcn_mfma_f32_16x16x32_bf16(pf1, vf1, oacc[j], 0, 0, 0);
        }
    }

    float inv[4];
    #pragma unroll
    for (int r = 0; r < 4; ++r) {
        float s = lrow[r];
        #pragma unroll
        for (int d = 1; d < 16; d <<= 1) s += __shfl_xor(s, d);
        inv[r] = 1.0f / s;
    }
    #pragma unroll
    for (int j = 0; j < 4; ++j) {
        int col = hcol + j * 16 + lm;
        #pragma unroll
        for (int r = 0; r < 4; ++r) {
            size_t row = qrow0 + wave * 16 + quad * 4 + r;
            o[row * 512 + col] = f2bf(oacc[j][r] * inv[r]);
        }
    }
}

// ---------------------------------------------------------------------------
extern "C" void kernel_launch(void* const* d_in, const int* in_sizes, int n_in,
                              void* d_out, int out_size, void* d_ws, size_t ws_size,
                              hipStream_t stream)
{
    const float* x   = (const float*)d_in[0];
    const float* ctx = (const float*)d_in[1];
    const float* Wq  = (const float*)d_in[2];
    const float* Wk  = (const float*)d_in[3];
    const float* Wv  = (const float*)d_in[4];
    const float* Wo  = (const float*)d_in[5];
    const float* bo  = (const float*)d_in[6];

    char* ws = (char*)d_ws;
    short* xb   = (short*)(ws);                                    // 8 MB
    short* cb   = (short*)(ws + (8u << 20));                       // 6 MB
    short* wqT  = (short*)(ws + (14u << 20));                      // 0.5 MB
    short* wkvT = (short*)(ws + (14u << 20) + (512u << 10));       // 1.5 MB
    short* woT  = (short*)(ws + (16u << 20));                      // 0.5 MB
    short* qb   = (short*)(ws + (16u << 20) + (512u << 10));       // 8 MB
    short* kvb  = (short*)(ws + (24u << 20) + (512u << 10));       // 8 MB
    short* ob   = xb;   // xb dead after QKV GEMM
    short* vT   = cb;   // cb dead after QKV GEMM

    prep_kernel<<<8448, 256, 0, stream>>>(x, ctx, Wq, Wk, Wv, Wo,
                                          xb, cb, wqT, wkvT, woT);
    qkv_kernel<<<1024, 256, 0, stream>>>(xb, cb, wqT, wkvT, qb, kvb);
    vtrans_kernel<<<dim3(16, 32, 4), 256, 0, stream>>>(kvb + 512, vT);
    attn_kernel<<<dim3(32, 8, 4), 256, 0, stream>>>(qb, kvb, vT, ob);
    ogemm_kernel<<<1024, 256, 0, stream>>>(ob, woT, bo, (float*)d_out);
}